// Round 14
// baseline (227.944 us; speedup 1.0000x reference)
//
#include <hip/hip_runtime.h>
#include <hip/hip_bf16.h>

#define DEV __device__ __forceinline__

typedef __attribute__((ext_vector_type(8))) short bf16x8;
typedef __attribute__((ext_vector_type(4))) float f32x4;

// Problem constants
#define BB 4
#define SS 2048
#define DD 1024
#define HH 16
#define HDD 64
#define MM (BB * SS)   // 8192
#define NQT (SS / 128) // 16 q-tiles of 128 rows

DEV short f2bf(float f) {
  unsigned u = __builtin_bit_cast(unsigned, f);
  u = u + 0x7fffu + ((u >> 16) & 1u);
  return (short)(u >> 16);
}

DEV float fexp2(float x) {
  float r;
  asm("v_exp_f32 %0, %1" : "=v"(r) : "v"(x));
  return r;
}
DEV float frcp(float x) {
  float r;
  asm("v_rcp_f32 %0, %1" : "=v"(r) : "v"(x));
  return r;
}
DEV unsigned cvtpk(float a, float b) {
  unsigned r;
  asm("v_cvt_pk_bf16_f32 %0, %1, %2" : "=v"(r) : "v"(a), "v"(b));
  return r;
}

DEV void gload_lds16(const void* g, void* l) {
  __builtin_amdgcn_global_load_lds((const __attribute__((address_space(1))) void*)g,
                                   (__attribute__((address_space(3))) void*)l, 16, 0, 0);
}

// T1: XCD-chunked bijective blockIdx swizzle (grids here are % 8 == 0).
DEV int2 xcd_swizzle() {
  const int nx = gridDim.x;
  const int nwg = nx * gridDim.y;
  const int o = blockIdx.y * nx + blockIdx.x;
  const int wid = (o & 7) * (nwg >> 3) + (o >> 3);
  int2 r; r.x = wid % nx; r.y = wid / nx;
  return r;
}

DEV void cast_range(const float* __restrict__ in, unsigned long long* __restrict__ out,
                    int n4, int start, int stride) {
  for (int i = start; i < n4; i += stride) {
    const float4 f = ((const float4*)in)[i];
    unsigned long long a = (unsigned long long)(unsigned short)f2bf(f.x)
        | ((unsigned long long)(unsigned short)f2bf(f.y) << 16)
        | ((unsigned long long)(unsigned short)f2bf(f.z) << 32)
        | ((unsigned long long)(unsigned short)f2bf(f.w) << 48);
    out[i] = a;
  }
}

__global__ __launch_bounds__(256)
void cast3_f32_bf16(const float* __restrict__ x, unsigned long long* __restrict__ ox, int nx4,
                    const float* __restrict__ wq, unsigned long long* __restrict__ owq, int nwq4,
                    const float* __restrict__ wo, unsigned long long* __restrict__ owo, int nwo4) {
  const int start = blockIdx.x * 256 + threadIdx.x;
  const int stride = gridDim.x * 256;
  cast_range(x, ox, nx4, start, stride);
  cast_range(wq, owq, nwq4, start, stride);
  cast_range(wo, owo, nwo4, start, stride);
}

// Fine-phase pipelined GEMM (T3/T4/T5): C = A[M,K]*Bw[N,K]^T + bias.
// BK=32: each K-tile is one phase = {counted vmcnt -> barrier -> issue tile
// t+3 gloads -> ds_read 12 frags -> lgkmcnt(0)+sched_barrier -> setprio(1)
// FMxFN MFMA setprio(0)}. 4 rotating LDS buffers, 3-deep prefetch, steady
// wait vmcnt(8) (2 tiles x 4 loads in flight; 0 only at the tail). One
// barrier per phase (race-free: reads of tile t end at its lgkmcnt(0);
// writes to that buffer (tile t+4) issue after the NEXT entry barrier).
// At BK=32 (64B rows) every wave frag read is a contiguous 1KB -> bank-
// conflict-free with NO swizzle. Phase density matches m201 (0.375 reads/MFMA).
// EPI=0: scatter Q (pre-scaled log2e/8) / K / V (tau-interleaved) bf16.
template<int EPI, int BM, int BN, int WN, int THREADS>
__global__ __launch_bounds__(THREADS, 2)
void gemm_p4(const short* __restrict__ A, const short* __restrict__ Bw,
             const float* __restrict__ bias,
             short* __restrict__ qo, short* __restrict__ ko, short* __restrict__ vo,
             float* __restrict__ co,
             int M, int N, int K) {
  constexpr int NW = THREADS / 64;
  constexpr int WM = NW / WN;
  constexpr int WTM = BM / WM, WTN = BN / WN;
  constexpr int FM = WTM / 16, FN = WTN / 16;
  constexpr int NA = (4 * BM) / THREADS;   // A 16B-chunks per thread per tile
  constexpr int NB = (4 * BN) / THREADS;
  __shared__ short sA[4][BM * 32];
  __shared__ short sB[4][BN * 32];
  const int tid = threadIdx.x;
  const int lane = tid & 63;
  const int wid = tid >> 6;
  const int wm = wid / WN, wn = wid % WN;
  const int2 sw = xcd_swizzle();
  const int m0 = sw.y * BM, n0 = sw.x * BN;
  const int lr = lane & 15, lg = lane >> 4;

  // staging chunks: tile row = c>>2 (4 x 16B per 64B row), linear LDS dest
  int aro[NA], aco[NA], ado[NA];
#pragma unroll
  for (int i = 0; i < NA; ++i) {
    const int c = i * THREADS + tid;
    aro[i] = c >> 2; aco[i] = (c & 3) * 8; ado[i] = c * 8;
  }
  int bro[NB], bco[NB], bdo_[NB];
#pragma unroll
  for (int i = 0; i < NB; ++i) {
    const int c = i * THREADS + tid;
    bro[i] = c >> 2; bco[i] = (c & 3) * 8; bdo_[i] = c * 8;
  }

  const int nkt = K >> 5;   // 32

  // prologue: tiles 0..2 into buffers 0..2 (12 loads outstanding)
#pragma unroll
  for (int p = 0; p < 3; ++p) {
    const int kk = p << 5;
#pragma unroll
    for (int i = 0; i < NA; ++i)
      gload_lds16(A + (size_t)(m0 + aro[i]) * K + kk + aco[i], &sA[p][ado[i]]);
#pragma unroll
    for (int i = 0; i < NB; ++i)
      gload_lds16(Bw + (size_t)(n0 + bro[i]) * K + kk + bco[i], &sB[p][bdo_[i]]);
  }

  f32x4 acc[FM][FN] = {};
  for (int t = 0; t < nkt; ++t) {
    const int buf = t & 3;
    if (t + 2 < nkt)      asm volatile("s_waitcnt vmcnt(8)" ::: "memory");
    else if (t + 1 < nkt) asm volatile("s_waitcnt vmcnt(4)" ::: "memory");
    else                  asm volatile("s_waitcnt vmcnt(0)" ::: "memory");
    __builtin_amdgcn_s_barrier();
    __builtin_amdgcn_sched_barrier(0);

    if (t + 3 < nkt) {   // stage tile t+3 into the buffer freed by tile t-1
      const int kk = (t + 3) << 5;
      const int pb = (t + 3) & 3;
#pragma unroll
      for (int i = 0; i < NA; ++i)
        gload_lds16(A + (size_t)(m0 + aro[i]) * K + kk + aco[i], &sA[pb][ado[i]]);
#pragma unroll
      for (int i = 0; i < NB; ++i)
        gload_lds16(Bw + (size_t)(n0 + bro[i]) * K + kk + bco[i], &sB[pb][bdo_[i]]);
    }

    bf16x8 afr[FM], bfr[FN];
#pragma unroll
    for (int i = 0; i < FM; ++i)
      afr[i] = *(const bf16x8*)&sA[buf][(wm * WTM + i * 16 + lr) * 32 + lg * 8];
#pragma unroll
    for (int j = 0; j < FN; ++j)
      bfr[j] = *(const bf16x8*)&sB[buf][(wn * WTN + j * 16 + lr) * 32 + lg * 8];
    asm volatile("s_waitcnt lgkmcnt(0)" ::: "memory");
    __builtin_amdgcn_sched_barrier(0);

    __builtin_amdgcn_s_setprio(1);
#pragma unroll
    for (int i = 0; i < FM; ++i)
#pragma unroll
      for (int j = 0; j < FN; ++j)
        acc[i][j] = __builtin_amdgcn_mfma_f32_16x16x32_bf16(afr[i], bfr[j], acc[i][j], 0, 0, 0);
    __builtin_amdgcn_s_setprio(0);
  }

#pragma unroll
  for (int i = 0; i < FM; ++i) {
#pragma unroll
    for (int j = 0; j < FN; ++j) {
#pragma unroll
      for (int r = 0; r < 4; ++r) {
        const int row = m0 + wm * WTM + i * 16 + lg * 4 + r;
        const int col = n0 + wn * WTN + j * 16 + lr;
        float v = acc[i][j][r] + bias[col];
        if (EPI == 0) {
          const int part = col >> 10, oo = col & 1023;
          const int h = oo >> 6, d = oo & 63;
          const int bb = row >> 11, s = row & 2047;
          if (part == 0)
            qo[(((size_t)bb * HH + h) * SS + s) * HDD + d] = f2bf(v * 0.18033688f); // 0.125*log2(e)
          else if (part == 1)
            ko[(((size_t)bb * HH + h) * SS + s) * HDD + d] = f2bf(v);
          else {
            const int q2 = (s >> 2) & 15;
            const int tau = (q2 & 8) | ((q2 & 3) << 1) | ((q2 >> 2) & 1);
            vo[(((size_t)bb * HH + h) * HDD + d) * SS + (s & ~63) + (tau << 2) + (s & 3)] = f2bf(v);
          }
        } else {
          co[(size_t)row * N + col] = v;
        }
      }
    }
  }
}

// Flash attention (round-11 version, unchanged): QBLK=128, swapped-operand
// QK^T, P in registers, tau-interleaved V -> single-b128 PV reads, K/V dbuf
// LDS, exp2 softmax, defer-max, T1 XCD swizzle.
__global__ __launch_bounds__(256)
void attn_fwd(const short* __restrict__ Q, const short* __restrict__ K,
              const short* __restrict__ V, short* __restrict__ Y) {
  __shared__ short sK[2][64 * 64];
  __shared__ short sV[2][64 * 64];
  const int2 sw = xcd_swizzle();
  const int bh = sw.y;
  const int bx = sw.x;
  const int tid = threadIdx.x, lane = tid & 63, w = tid >> 6;
  const size_t bqk = (size_t)bh * (SS * HDD);
  const size_t bv  = (size_t)bh * (HDD * SS);
  const int b = bh >> 4, h = bh & 15;
  const int lr = lane & 15;
  const int lg = lane >> 4;
  const int lm = lr & 7;

  const int e0 = w * 64 + lane;
  const int e1 = 256 + e0;
  const int r0 = e0 >> 3, s0 = ((e0 & 7) ^ (r0 & 7)) * 8;
  const int r1 = e1 >> 3, s1 = ((e1 & 7) ^ (r1 & 7)) * 8;

  for (int qsel = 0; qsel < 2; ++qsel) {
    const int qt = qsel ? (NQT - 1 - bx) : bx;
    const int q0 = qt * 128;
    const int nkv = 2 * qt + 2;

    __syncthreads();

    {
      const short* gK = K + bqk;
      const short* gV = V + bv;
      gload_lds16(gK + (size_t)r0 * HDD + s0, &sK[0][e0 * 8]);
      gload_lds16(gV + (size_t)r0 * SS + s0, &sV[0][e0 * 8]);
      gload_lds16(gK + (size_t)r1 * HDD + s1, &sK[0][e1 * 8]);
      gload_lds16(gV + (size_t)r1 * SS + s1, &sV[0][e1 * 8]);
    }

    const int qbase = q0 + w * 32;
    bf16x8 qf[2][2];
#pragma unroll
    for (int g = 0; g < 2; ++g)
#pragma unroll
      for (int ks = 0; ks < 2; ++ks)
        qf[g][ks] = *(const bf16x8*)&Q[bqk + (size_t)(qbase + g * 16 + lr) * HDD + ks * 32 + lg * 8];

    f32x4 accO[2][4] = {};
    float m_[2] = {-1e30f, -1e30f}, l_[2] = {0.f, 0.f};

    int cur = 0;
    for (int kt = 0; kt < nkv; ++kt) {
      const int kc0 = kt * 64;
      __syncthreads();
      if (kt < nkv - 1) {
        const short* gK = K + bqk + (size_t)(kc0 + 64) * 64;
        const short* gV = V + bv + kc0 + 64;
        gload_lds16(gK + (size_t)r0 * HDD + s0, &sK[cur ^ 1][e0 * 8]);
        gload_lds16(gV + (size_t)r0 * SS + s0, &sV[cur ^ 1][e0 * 8]);
        gload_lds16(gK + (size_t)r1 * HDD + s1, &sK[cur ^ 1][e1 * 8]);
        gload_lds16(gV + (size_t)r1 * SS + s1, &sV[cur ^ 1][e1 * 8]);
      }

      f32x4 st[2][4] = {};
#pragma unroll
      for (int ks = 0; ks < 2; ++ks) {
#pragma unroll
        for (int nf = 0; nf < 4; ++nf) {
          const int row = nf * 16 + lr;
          const bf16x8 kf = *(const bf16x8*)&sK[cur][row * 64 + (((ks << 2) + lg) ^ lm) * 8];
          st[0][nf] = __builtin_amdgcn_mfma_f32_16x16x32_bf16(kf, qf[0][ks], st[0][nf], 0, 0, 0);
          st[1][nf] = __builtin_amdgcn_mfma_f32_16x16x32_bf16(kf, qf[1][ks], st[1][nf], 0, 0, 0);
        }
      }
      if (kt >= nkv - 2) {
#pragma unroll
        for (int g = 0; g < 2; ++g) {
          const int q = qbase + g * 16 + lr;
#pragma unroll
          for (int nf = 0; nf < 4; ++nf)
#pragma unroll
            for (int r = 0; r < 4; ++r) {
              const int k = kc0 + nf * 16 + lg * 4 + r;
              if (k > q) st[g][nf][r] = -1e30f;
            }
        }
      }

      unsigned u[2][4][2];
#pragma unroll
      for (int g = 0; g < 2; ++g) {
        float rm = -1e30f;
#pragma unroll
        for (int r = 0; r < 4; ++r)
          rm = fmaxf(rm, fmaxf(fmaxf(st[g][0][r], st[g][1][r]), fmaxf(st[g][2][r], st[g][3][r])));
        rm = fmaxf(rm, __shfl_xor(rm, 16));
        rm = fmaxf(rm, __shfl_xor(rm, 32));

        const bool need = rm > m_[g] + 11.5416f;
        if (__any(need)) {
          const float mn = fmaxf(m_[g], rm);
          const float scale = fexp2(m_[g] - mn);
          m_[g] = mn;
          l_[g] *= scale;
#pragma unroll
          for (int r = 0; r < 4; ++r) {
            const float scl = __shfl(scale, (lane & 48) + (lg << 2) + r);
#pragma unroll
            for (int df = 0; df < 4; ++df) accO[g][df][r] *= scl;
          }
        }

        float rs = 0.f;
#pragma unroll
        for (int nf = 0; nf < 4; ++nf)
#pragma unroll
          for (int r = 0; r < 4; ++r) {
            const float p = fexp2(st[g][nf][r] - m_[g]);
            st[g][nf][r] = p;
            rs += p;
          }
        rs += __shfl_xor(rs, 16);
        rs += __shfl_xor(rs, 32);
        l_[g] += rs;

#pragma unroll
        for (int nf = 0; nf < 4; ++nf) {
          u[g][nf][0] = cvtpk(st[g][nf][0], st[g][nf][1]);
          u[g][nf][1] = cvtpk(st[g][nf][2], st[g][nf][3]);
        }
      }

#pragma unroll
      for (int c = 0; c < 2; ++c) {
        int4 pw0, pw1;
        pw0.x = (int)u[0][2 * c][0]; pw0.y = (int)u[0][2 * c][1];
        pw0.z = (int)u[0][2 * c + 1][0]; pw0.w = (int)u[0][2 * c + 1][1];
        pw1.x = (int)u[1][2 * c][0]; pw1.y = (int)u[1][2 * c][1];
        pw1.z = (int)u[1][2 * c + 1][0]; pw1.w = (int)u[1][2 * c + 1][1];
        const bf16x8 pf0 = __builtin_bit_cast(bf16x8, pw0);
        const bf16x8 pf1 = __builtin_bit_cast(bf16x8, pw1);
        const int slot = (((c << 2) + lg) ^ lm) * 8;
#pragma unroll
        for (int df = 0; df < 4; ++df) {
          const bf16x8 vf = *(const bf16x8*)&sV[cur][(df * 16 + lr) * 64 + slot];
          accO[0][df] = __builtin_amdgcn_mfma_f32_16x16x32_bf16(pf0, vf, accO[0][df], 0, 0, 0);
          accO[1][df] = __builtin_amdgcn_mfma_f32_16x16x32_bf16(pf1, vf, accO[1][df], 0, 0, 0);
        }
      }
      cur ^= 1;
    }

#pragma unroll
    for (int g = 0; g < 2; ++g)
#pragma unroll
      for (int r = 0; r < 4; ++r) {
        const float lv = __shfl(l_[g], (lane & 48) + (lg << 2) + r);
        const float inv = frcp(lv);
        const int srow2 = qbase + g * 16 + lg * 4 + r;
#pragma unroll
        for (int df = 0; df < 4; ++df) {
          const int dcol = h * HDD + df * 16 + lr;
          Y[((size_t)b * SS + srow2) * DD + dcol] = f2bf(accO[g][df][r] * inv);
        }
      }
  }
}

extern "C" void kernel_launch(void* const* d_in, const int* in_sizes, int n_in,
                              void* d_out, int out_size, void* d_ws, size_t ws_size,
                              hipStream_t stream) {
  const float* x     = (const float*)d_in[0];
  const float* w_qkv = (const float*)d_in[1];
  const float* b_qkv = (const float*)d_in[2];
  const float* w_out = (const float*)d_in[3];
  const float* b_out = (const float*)d_in[4];
  float* out = (float*)d_out;

  const size_t nx = (size_t)MM * DD;        // 8388608
  const size_t nwq = (size_t)3 * DD * DD;   // 3145728
  const size_t nwo = (size_t)DD * DD;       // 1048576

  short* x_bf    = (short*)d_ws;
  short* wqkv_bf = x_bf + nx;
  short* wout_bf = wqkv_bf + nwq;
  short* q_ws    = wout_bf + nwo;
  short* k_ws    = q_ws + nx;
  short* v_ws    = k_ws + nx;
  short* y_ws    = v_ws + nx;

  cast3_f32_bf16<<<dim3(2048), dim3(256), 0, stream>>>(
      x, (unsigned long long*)x_bf, (int)(nx / 4),
      w_qkv, (unsigned long long*)wqkv_bf, (int)(nwq / 4),
      w_out, (unsigned long long*)wout_bf, (int)(nwo / 4));

  // GEMM1: QKV, 256x256 tiles, 8 waves 2Mx4N (wave 128x64), grid 12x32 = 384
  gemm_p4<0, 256, 256, 4, 512><<<dim3(3 * DD / 256, MM / 256), dim3(512), 0, stream>>>(
      x_bf, wqkv_bf, b_qkv, q_ws, k_ws, v_ws, nullptr, MM, 3 * DD, DD);

  attn_fwd<<<dim3(NQT / 2, BB * HH), dim3(256), 0, stream>>>(q_ws, k_ws, v_ws, y_ws);

  // GEMM2: out-proj, 128x128 tiles, 4 waves 2Mx2N (wave 64x64), grid 8x64 = 512
  gemm_p4<1, 128, 128, 2, 256><<<dim3(DD / 128, MM / 128), dim3(256), 0, stream>>>(
      y_ws, wout_bf, b_out, nullptr, nullptr, nullptr, out, MM, DD, DD);
}

// Round 15
// 206.590 us; speedup vs baseline: 1.1034x; 1.1034x over previous
//
#include <hip/hip_runtime.h>
#include <hip/hip_bf16.h>

#define DEV __device__ __forceinline__

typedef __attribute__((ext_vector_type(8))) short bf16x8;
typedef __attribute__((ext_vector_type(4))) float f32x4;

// Problem constants
#define BB 4
#define SS 2048
#define DD 1024
#define HH 16
#define HDD 64
#define MM (BB * SS)   // 8192
#define NQT (SS / 128) // 16 q-tiles of 128 rows

DEV short f2bf(float f) {
  unsigned u = __builtin_bit_cast(unsigned, f);
  u = u + 0x7fffu + ((u >> 16) & 1u);
  return (short)(u >> 16);
}

DEV float fexp2(float x) {
  float r;
  asm("v_exp_f32 %0, %1" : "=v"(r) : "v"(x));
  return r;
}
DEV float frcp(float x) {
  float r;
  asm("v_rcp_f32 %0, %1" : "=v"(r) : "v"(x));
  return r;
}
DEV unsigned cvtpk(float a, float b) {
  unsigned r;
  asm("v_cvt_pk_bf16_f32 %0, %1, %2" : "=v"(r) : "v"(a), "v"(b));
  return r;
}

DEV void gload_lds16(const void* g, void* l) {
  __builtin_amdgcn_global_load_lds((const __attribute__((address_space(1))) void*)g,
                                   (__attribute__((address_space(3))) void*)l, 16, 0, 0);
}

// T1: XCD-chunked bijective blockIdx swizzle (grids here are % 8 == 0).
DEV int2 xcd_swizzle() {
  const int nx = gridDim.x;
  const int nwg = nx * gridDim.y;
  const int o = blockIdx.y * nx + blockIdx.x;
  const int wid = (o & 7) * (nwg >> 3) + (o >> 3);
  int2 r; r.x = wid % nx; r.y = wid / nx;
  return r;
}

DEV void cast_range(const float* __restrict__ in, unsigned long long* __restrict__ out,
                    int n4, int start, int stride) {
  for (int i = start; i < n4; i += stride) {
    const float4 f = ((const float4*)in)[i];
    unsigned long long a = (unsigned long long)(unsigned short)f2bf(f.x)
        | ((unsigned long long)(unsigned short)f2bf(f.y) << 16)
        | ((unsigned long long)(unsigned short)f2bf(f.z) << 32)
        | ((unsigned long long)(unsigned short)f2bf(f.w) << 48);
    out[i] = a;
  }
}

__global__ __launch_bounds__(256)
void cast3_f32_bf16(const float* __restrict__ x, unsigned long long* __restrict__ ox, int nx4,
                    const float* __restrict__ wq, unsigned long long* __restrict__ owq, int nwq4,
                    const float* __restrict__ wo, unsigned long long* __restrict__ owo, int nwo4) {
  const int start = blockIdx.x * 256 + threadIdx.x;
  const int stride = gridDim.x * 256;
  cast_range(x, ox, nx4, start, stride);
  cast_range(wq, owq, nwq4, start, stride);
  cast_range(wo, owo, nwo4, start, stride);
}

// Counted-vmcnt 3-buffer pipelined GEMM (m248-style T3/T4/T5):
// C = A[M,K]*Bw[N,K]^T + bias. BM=256, BN=128, BK=64, 512 thr / 8 waves
// (4Mx2N, wave 64x64). 3 rotating LDS buffers (144KB), 2-tile prefetch depth:
//   entry: vmcnt(6) [t+1's 6 loads stay in flight; 0 only on last tile]
//   barrier; issue tile t+2's 6 gload_lds into buf[(t+2)%3]
//   2 sub-phases (ks=0,1): 8 swizzled ds_read_b128 -> lgkmcnt(0)+sched_barrier
//                          -> setprio(1) 16 MFMA setprio(0)
// Race-free with one barrier/tile: buf(t%3) is rewritten (tile t+3) only
// after the t+1 entry barrier, which follows all waves' reads of tile t.
// XOR-swizzled staging source / swizzled read slot (round-10 proven, 0 conflicts).
// EPI=0: scatter Q (pre-scaled log2e/8) / K / V (tau-interleaved) bf16.
template<int EPI>
__global__ __launch_bounds__(512, 1)
void gemm_c3(const short* __restrict__ A, const short* __restrict__ Bw,
             const float* __restrict__ bias,
             short* __restrict__ qo, short* __restrict__ ko, short* __restrict__ vo,
             float* __restrict__ co,
             int M, int N, int K) {
  __shared__ short sA[3][256 * 64];
  __shared__ short sB[3][128 * 64];
  const int tid = threadIdx.x;
  const int lane = tid & 63;
  const int wid = tid >> 6;
  const int wm = wid >> 1, wn = wid & 1;     // 4M x 2N waves, wave tile 64x64
  const int2 sw = xcd_swizzle();
  const int m0 = sw.y * 256, n0 = sw.x * 128;
  const int lr = lane & 15, lg = lane >> 4;
  const int lm = lr & 7;

  // staging: element e (16B chunk), row = e>>3 (8 chunks per 128B row),
  // LDS dest linear, global source col-chunk pre-swizzled (e&7)^(row&7).
  int aro[4], aso[4], ado[4];
#pragma unroll
  for (int i = 0; i < 4; ++i) {
    const int e = i * 512 + tid;
    const int row = e >> 3;
    aro[i] = row; aso[i] = ((e & 7) ^ (row & 7)) * 8; ado[i] = e * 8;
  }
  int bro[2], bso[2], bdo_[2];
#pragma unroll
  for (int i = 0; i < 2; ++i) {
    const int e = i * 512 + tid;
    const int row = e >> 3;
    bro[i] = row; bso[i] = ((e & 7) ^ (row & 7)) * 8; bdo_[i] = e * 8;
  }

  const int nkt = K >> 6;   // 16

  // prologue: tiles 0,1 into buffers 0,1 (12 loads outstanding)
#pragma unroll
  for (int p = 0; p < 2; ++p) {
    const int kk = p << 6;
#pragma unroll
    for (int i = 0; i < 4; ++i)
      gload_lds16(A + (size_t)(m0 + aro[i]) * K + kk + aso[i], &sA[p][ado[i]]);
#pragma unroll
    for (int i = 0; i < 2; ++i)
      gload_lds16(Bw + (size_t)(n0 + bro[i]) * K + kk + bso[i], &sB[p][bdo_[i]]);
  }

  f32x4 acc[4][4] = {};
  int buf = 0;
  for (int t = 0; t < nkt; ++t) {
    if (t + 1 < nkt) asm volatile("s_waitcnt vmcnt(6)" ::: "memory");
    else             asm volatile("s_waitcnt vmcnt(0)" ::: "memory");
    __builtin_amdgcn_s_barrier();
    __builtin_amdgcn_sched_barrier(0);

    if (t + 2 < nkt) {   // stage t+2 into the buffer freed after t-1
      const int kk = (t + 2) << 6;
      const int pb = (buf + 2 >= 3) ? buf - 1 : buf + 2;
#pragma unroll
      for (int i = 0; i < 4; ++i)
        gload_lds16(A + (size_t)(m0 + aro[i]) * K + kk + aso[i], &sA[pb][ado[i]]);
#pragma unroll
      for (int i = 0; i < 2; ++i)
        gload_lds16(Bw + (size_t)(n0 + bro[i]) * K + kk + bso[i], &sB[pb][bdo_[i]]);
    }

#pragma unroll
    for (int ks = 0; ks < 2; ++ks) {
      const int slot = (((ks << 2) + lg) ^ lm) * 8;
      bf16x8 afr[4], bfr[4];
#pragma unroll
      for (int i = 0; i < 4; ++i)
        afr[i] = *(const bf16x8*)&sA[buf][(wm * 64 + i * 16 + lr) * 64 + slot];
#pragma unroll
      for (int j = 0; j < 4; ++j)
        bfr[j] = *(const bf16x8*)&sB[buf][(wn * 64 + j * 16 + lr) * 64 + slot];
      asm volatile("s_waitcnt lgkmcnt(0)" ::: "memory");
      __builtin_amdgcn_sched_barrier(0);
      __builtin_amdgcn_s_setprio(1);
#pragma unroll
      for (int i = 0; i < 4; ++i)
#pragma unroll
        for (int j = 0; j < 4; ++j)
          acc[i][j] = __builtin_amdgcn_mfma_f32_16x16x32_bf16(afr[i], bfr[j], acc[i][j], 0, 0, 0);
      __builtin_amdgcn_s_setprio(0);
    }
    buf = (buf + 1 >= 3) ? 0 : buf + 1;
  }

#pragma unroll
  for (int i = 0; i < 4; ++i) {
#pragma unroll
    for (int j = 0; j < 4; ++j) {
#pragma unroll
      for (int r = 0; r < 4; ++r) {
        const int row = m0 + wm * 64 + i * 16 + lg * 4 + r;
        const int col = n0 + wn * 64 + j * 16 + lr;
        float v = acc[i][j][r] + bias[col];
        if (EPI == 0) {
          const int part = col >> 10, oo = col & 1023;
          const int h = oo >> 6, d = oo & 63;
          const int bb = row >> 11, s = row & 2047;
          if (part == 0)
            qo[(((size_t)bb * HH + h) * SS + s) * HDD + d] = f2bf(v * 0.18033688f); // 0.125*log2(e)
          else if (part == 1)
            ko[(((size_t)bb * HH + h) * SS + s) * HDD + d] = f2bf(v);
          else {
            const int q2 = (s >> 2) & 15;
            const int tau = (q2 & 8) | ((q2 & 3) << 1) | ((q2 >> 2) & 1);
            vo[(((size_t)bb * HH + h) * HDD + d) * SS + (s & ~63) + (tau << 2) + (s & 3)] = f2bf(v);
          }
        } else {
          co[(size_t)row * N + col] = v;
        }
      }
    }
  }
}

// Flash attention (round-11 version, unchanged): QBLK=128, swapped-operand
// QK^T, P in registers, tau-interleaved V -> single-b128 PV reads, K/V dbuf
// LDS, exp2 softmax, defer-max, T1 XCD swizzle.
__global__ __launch_bounds__(256)
void attn_fwd(const short* __restrict__ Q, const short* __restrict__ K,
              const short* __restrict__ V, short* __restrict__ Y) {
  __shared__ short sK[2][64 * 64];
  __shared__ short sV[2][64 * 64];
  const int2 sw = xcd_swizzle();
  const int bh = sw.y;
  const int bx = sw.x;
  const int tid = threadIdx.x, lane = tid & 63, w = tid >> 6;
  const size_t bqk = (size_t)bh * (SS * HDD);
  const size_t bv  = (size_t)bh * (HDD * SS);
  const int b = bh >> 4, h = bh & 15;
  const int lr = lane & 15;
  const int lg = lane >> 4;
  const int lm = lr & 7;

  const int e0 = w * 64 + lane;
  const int e1 = 256 + e0;
  const int r0 = e0 >> 3, s0 = ((e0 & 7) ^ (r0 & 7)) * 8;
  const int r1 = e1 >> 3, s1 = ((e1 & 7) ^ (r1 & 7)) * 8;

  for (int qsel = 0; qsel < 2; ++qsel) {
    const int qt = qsel ? (NQT - 1 - bx) : bx;
    const int q0 = qt * 128;
    const int nkv = 2 * qt + 2;

    __syncthreads();

    {
      const short* gK = K + bqk;
      const short* gV = V + bv;
      gload_lds16(gK + (size_t)r0 * HDD + s0, &sK[0][e0 * 8]);
      gload_lds16(gV + (size_t)r0 * SS + s0, &sV[0][e0 * 8]);
      gload_lds16(gK + (size_t)r1 * HDD + s1, &sK[0][e1 * 8]);
      gload_lds16(gV + (size_t)r1 * SS + s1, &sV[0][e1 * 8]);
    }

    const int qbase = q0 + w * 32;
    bf16x8 qf[2][2];
#pragma unroll
    for (int g = 0; g < 2; ++g)
#pragma unroll
      for (int ks = 0; ks < 2; ++ks)
        qf[g][ks] = *(const bf16x8*)&Q[bqk + (size_t)(qbase + g * 16 + lr) * HDD + ks * 32 + lg * 8];

    f32x4 accO[2][4] = {};
    float m_[2] = {-1e30f, -1e30f}, l_[2] = {0.f, 0.f};

    int cur = 0;
    for (int kt = 0; kt < nkv; ++kt) {
      const int kc0 = kt * 64;
      __syncthreads();
      if (kt < nkv - 1) {
        const short* gK = K + bqk + (size_t)(kc0 + 64) * 64;
        const short* gV = V + bv + kc0 + 64;
        gload_lds16(gK + (size_t)r0 * HDD + s0, &sK[cur ^ 1][e0 * 8]);
        gload_lds16(gV + (size_t)r0 * SS + s0, &sV[cur ^ 1][e0 * 8]);
        gload_lds16(gK + (size_t)r1 * HDD + s1, &sK[cur ^ 1][e1 * 8]);
        gload_lds16(gV + (size_t)r1 * SS + s1, &sV[cur ^ 1][e1 * 8]);
      }

      f32x4 st[2][4] = {};
#pragma unroll
      for (int ks = 0; ks < 2; ++ks) {
#pragma unroll
        for (int nf = 0; nf < 4; ++nf) {
          const int row = nf * 16 + lr;
          const bf16x8 kf = *(const bf16x8*)&sK[cur][row * 64 + (((ks << 2) + lg) ^ lm) * 8];
          st[0][nf] = __builtin_amdgcn_mfma_f32_16x16x32_bf16(kf, qf[0][ks], st[0][nf], 0, 0, 0);
          st[1][nf] = __builtin_amdgcn_mfma_f32_16x16x32_bf16(kf, qf[1][ks], st[1][nf], 0, 0, 0);
        }
      }
      if (kt >= nkv - 2) {
#pragma unroll
        for (int g = 0; g < 2; ++g) {
          const int q = qbase + g * 16 + lr;
#pragma unroll
          for (int nf = 0; nf < 4; ++nf)
#pragma unroll
            for (int r = 0; r < 4; ++r) {
              const int k = kc0 + nf * 16 + lg * 4 + r;
              if (k > q) st[g][nf][r] = -1e30f;
            }
        }
      }

      unsigned u[2][4][2];
#pragma unroll
      for (int g = 0; g < 2; ++g) {
        float rm = -1e30f;
#pragma unroll
        for (int r = 0; r < 4; ++r)
          rm = fmaxf(rm, fmaxf(fmaxf(st[g][0][r], st[g][1][r]), fmaxf(st[g][2][r], st[g][3][r])));
        rm = fmaxf(rm, __shfl_xor(rm, 16));
        rm = fmaxf(rm, __shfl_xor(rm, 32));

        const bool need = rm > m_[g] + 11.5416f;
        if (__any(need)) {
          const float mn = fmaxf(m_[g], rm);
          const float scale = fexp2(m_[g] - mn);
          m_[g] = mn;
          l_[g] *= scale;
#pragma unroll
          for (int r = 0; r < 4; ++r) {
            const float scl = __shfl(scale, (lane & 48) + (lg << 2) + r);
#pragma unroll
            for (int df = 0; df < 4; ++df) accO[g][df][r] *= scl;
          }
        }

        float rs = 0.f;
#pragma unroll
        for (int nf = 0; nf < 4; ++nf)
#pragma unroll
          for (int r = 0; r < 4; ++r) {
            const float p = fexp2(st[g][nf][r] - m_[g]);
            st[g][nf][r] = p;
            rs += p;
          }
        rs += __shfl_xor(rs, 16);
        rs += __shfl_xor(rs, 32);
        l_[g] += rs;

#pragma unroll
        for (int nf = 0; nf < 4; ++nf) {
          u[g][nf][0] = cvtpk(st[g][nf][0], st[g][nf][1]);
          u[g][nf][1] = cvtpk(st[g][nf][2], st[g][nf][3]);
        }
      }

#pragma unroll
      for (int c = 0; c < 2; ++c) {
        int4 pw0, pw1;
        pw0.x = (int)u[0][2 * c][0]; pw0.y = (int)u[0][2 * c][1];
        pw0.z = (int)u[0][2 * c + 1][0]; pw0.w = (int)u[0][2 * c + 1][1];
        pw1.x = (int)u[1][2 * c][0]; pw1.y = (int)u[1][2 * c][1];
        pw1.z = (int)u[1][2 * c + 1][0]; pw1.w = (int)u[1][2 * c + 1][1];
        const bf16x8 pf0 = __builtin_bit_cast(bf16x8, pw0);
        const bf16x8 pf1 = __builtin_bit_cast(bf16x8, pw1);
        const int slot = (((c << 2) + lg) ^ lm) * 8;
#pragma unroll
        for (int df = 0; df < 4; ++df) {
          const bf16x8 vf = *(const bf16x8*)&sV[cur][(df * 16 + lr) * 64 + slot];
          accO[0][df] = __builtin_amdgcn_mfma_f32_16x16x32_bf16(pf0, vf, accO[0][df], 0, 0, 0);
          accO[1][df] = __builtin_amdgcn_mfma_f32_16x16x32_bf16(pf1, vf, accO[1][df], 0, 0, 0);
        }
      }
      cur ^= 1;
    }

#pragma unroll
    for (int g = 0; g < 2; ++g)
#pragma unroll
      for (int r = 0; r < 4; ++r) {
        const float lv = __shfl(l_[g], (lane & 48) + (lg << 2) + r);
        const float inv = frcp(lv);
        const int srow2 = qbase + g * 16 + lg * 4 + r;
#pragma unroll
        for (int df = 0; df < 4; ++df) {
          const int dcol = h * HDD + df * 16 + lr;
          Y[((size_t)b * SS + srow2) * DD + dcol] = f2bf(accO[g][df][r] * inv);
        }
      }
  }
}

extern "C" void kernel_launch(void* const* d_in, const int* in_sizes, int n_in,
                              void* d_out, int out_size, void* d_ws, size_t ws_size,
                              hipStream_t stream) {
  const float* x     = (const float*)d_in[0];
  const float* w_qkv = (const float*)d_in[1];
  const float* b_qkv = (const float*)d_in[2];
  const float* w_out = (const float*)d_in[3];
  const float* b_out = (const float*)d_in[4];
  float* out = (float*)d_out;

  const size_t nx = (size_t)MM * DD;        // 8388608
  const size_t nwq = (size_t)3 * DD * DD;   // 3145728
  const size_t nwo = (size_t)DD * DD;       // 1048576

  short* x_bf    = (short*)d_ws;
  short* wqkv_bf = x_bf + nx;
  short* wout_bf = wqkv_bf + nwq;
  short* q_ws    = wout_bf + nwo;
  short* k_ws    = q_ws + nx;
  short* v_ws    = k_ws + nx;
  short* y_ws    = v_ws + nx;

  cast3_f32_bf16<<<dim3(2048), dim3(256), 0, stream>>>(
      x, (unsigned long long*)x_bf, (int)(nx / 4),
      w_qkv, (unsigned long long*)wqkv_bf, (int)(nwq / 4),
      w_out, (unsigned long long*)wout_bf, (int)(nwo / 4));

  // GEMM1: QKV, 256x128 tiles, grid 24x32 = 768 (3 perfect rounds)
  gemm_c3<0><<<dim3(3 * DD / 128, MM / 256), dim3(512), 0, stream>>>(
      x_bf, wqkv_bf, b_qkv, q_ws, k_ws, v_ws, nullptr, MM, 3 * DD, DD);

  attn_fwd<<<dim3(NQT / 2, BB * HH), dim3(256), 0, stream>>>(q_ws, k_ws, v_ws, y_ws);

  // GEMM2: out-proj, 256x128 tiles, grid 8x32 = 256 (1 perfect round)
  gemm_c3<1><<<dim3(DD / 128, MM / 256), dim3(512), 0, stream>>>(
      y_ws, wout_bf, b_out, nullptr, nullptr, nullptr, out, MM, DD, DD);
}

// Round 16
// 190.404 us; speedup vs baseline: 1.1972x; 1.0850x over previous
//
#include <hip/hip_runtime.h>
#include <hip/hip_bf16.h>

#define DEV __device__ __forceinline__

typedef __attribute__((ext_vector_type(8))) short bf16x8;
typedef __attribute__((ext_vector_type(4))) float f32x4;

// Problem constants
#define BB 4
#define SS 2048
#define DD 1024
#define HH 16
#define HDD 64
#define MM (BB * SS)   // 8192
#define NQT (SS / 128) // 16 q-tiles of 128 rows

DEV short f2bf(float f) {
  unsigned u = __builtin_bit_cast(unsigned, f);
  u = u + 0x7fffu + ((u >> 16) & 1u);
  return (short)(u >> 16);
}

DEV float fexp2(float x) {
  float r;
  asm("v_exp_f32 %0, %1" : "=v"(r) : "v"(x));
  return r;
}
DEV float frcp(float x) {
  float r;
  asm("v_rcp_f32 %0, %1" : "=v"(r) : "v"(x));
  return r;
}
DEV unsigned cvtpk(float a, float b) {
  unsigned r;
  asm("v_cvt_pk_bf16_f32 %0, %1, %2" : "=v"(r) : "v"(a), "v"(b));
  return r;
}

DEV void gload_lds16(const void* g, void* l) {
  __builtin_amdgcn_global_load_lds((const __attribute__((address_space(1))) void*)g,
                                   (__attribute__((address_space(3))) void*)l, 16, 0, 0);
}

// T1: XCD-chunked bijective blockIdx swizzle (grids here are % 8 == 0).
DEV int2 xcd_swizzle() {
  const int nx = gridDim.x;
  const int nwg = nx * gridDim.y;
  const int o = blockIdx.y * nx + blockIdx.x;
  const int wid = (o & 7) * (nwg >> 3) + (o >> 3);
  int2 r; r.x = wid % nx; r.y = wid / nx;
  return r;
}

DEV void cast_range(const float* __restrict__ in, unsigned long long* __restrict__ out,
                    int n4, int start, int stride) {
  for (int i = start; i < n4; i += stride) {
    const float4 f = ((const float4*)in)[i];
    unsigned long long a = (unsigned long long)(unsigned short)f2bf(f.x)
        | ((unsigned long long)(unsigned short)f2bf(f.y) << 16)
        | ((unsigned long long)(unsigned short)f2bf(f.z) << 32)
        | ((unsigned long long)(unsigned short)f2bf(f.w) << 48);
    out[i] = a;
  }
}

__global__ __launch_bounds__(256)
void cast3_f32_bf16(const float* __restrict__ x, unsigned long long* __restrict__ ox, int nx4,
                    const float* __restrict__ wq, unsigned long long* __restrict__ owq, int nwq4,
                    const float* __restrict__ wo, unsigned long long* __restrict__ owo, int nwo4) {
  const int start = blockIdx.x * 256 + threadIdx.x;
  const int stride = gridDim.x * 256;
  cast_range(x, ox, nx4, start, stride);
  cast_range(wq, owq, nwq4, start, stride);
  cast_range(wo, owo, nwo4, start, stride);
}

// Max-TLP GEMM: C = A[M,K]*Bw[N,K]^T + bias. 128x128 tile, 256 thr/4 waves,
// SINGLE 32KB LDS buffer -> 4 blocks/CU (16 waves/CU). The vmcnt(0)+barrier
// drain inside each block is hidden by the other 3 resident blocks (m114
// cross-block wave overlap) instead of by intra-block pipelining (r12-r15
// all showed deep pipelines lose more via occupancy than they gain).
// XOR-swizzled staging source / swizzled read slot (conflict-free b128, r10).
// T1 XCD chunking. EPI=0: scatter Q (pre-scaled log2e/8) / K / V (tau) bf16.
template<int EPI>
__global__ __launch_bounds__(256)
void gemm_bt(const short* __restrict__ A, const short* __restrict__ Bw,
             const float* __restrict__ bias,
             short* __restrict__ qo, short* __restrict__ ko, short* __restrict__ vo,
             float* __restrict__ co,
             int M, int N, int K) {
  __shared__ short sA[128 * 64];
  __shared__ short sB[128 * 64];
  const int lane = threadIdx.x & 63;
  const int wv = threadIdx.x >> 6;
  const int wm = wv >> 1, wn = wv & 1;
  const int2 sw = xcd_swizzle();
  const int m0 = sw.y * 128;
  const int n0 = sw.x * 128;
  const int lr = lane & 15;
  const int lg = lane >> 4;
  const int lm = lr & 7;

  // staging geometry: element e = i*256+tid (16B chunk), tile row = e>>3,
  // LDS dest linear at e*16B, global source col-chunk pre-swizzled (e&7)^(row&7)
  int srow[4], soff[4], doff[4];
#pragma unroll
  for (int i = 0; i < 4; ++i) {
    const int e = i * 256 + threadIdx.x;
    const int row = e >> 3;
    srow[i] = row;
    soff[i] = ((e & 7) ^ (row & 7)) * 8;   // shorts
    doff[i] = e * 8;                        // shorts
  }

  f32x4 acc[4][4] = {};
  const int nkt = K >> 6;
  for (int kt = 0; kt < nkt; ++kt) {
    const int k0 = kt << 6;
    if (kt) __syncthreads();   // prev tile's reads done before overwrite
#pragma unroll
    for (int i = 0; i < 4; ++i) {
      gload_lds16(A  + (size_t)(m0 + srow[i]) * K + k0 + soff[i], &sA[doff[i]]);
      gload_lds16(Bw + (size_t)(n0 + srow[i]) * K + k0 + soff[i], &sB[doff[i]]);
    }
    __syncthreads();           // staged (vmcnt drained by compiler)
#pragma unroll
    for (int ks = 0; ks < 2; ++ks) {
      const int slot = (((ks << 2) + lg) ^ lm) * 8;
      bf16x8 af[4], bf_[4];
#pragma unroll
      for (int i = 0; i < 4; ++i) {
        af[i]  = *(const bf16x8*)&sA[(wm * 64 + i * 16 + lr) * 64 + slot];
        bf_[i] = *(const bf16x8*)&sB[(wn * 64 + i * 16 + lr) * 64 + slot];
      }
#pragma unroll
      for (int i = 0; i < 4; ++i)
#pragma unroll
        for (int j = 0; j < 4; ++j)
          acc[i][j] = __builtin_amdgcn_mfma_f32_16x16x32_bf16(af[i], bf_[j], acc[i][j], 0, 0, 0);
    }
  }

#pragma unroll
  for (int i = 0; i < 4; ++i) {
#pragma unroll
    for (int j = 0; j < 4; ++j) {
#pragma unroll
      for (int r = 0; r < 4; ++r) {
        const int row = m0 + wm * 64 + i * 16 + lg * 4 + r;
        const int col = n0 + wn * 64 + j * 16 + lr;
        float v = acc[i][j][r] + bias[col];
        if (EPI == 0) {
          const int part = col >> 10, oo = col & 1023;
          const int h = oo >> 6, d = oo & 63;
          const int bb = row >> 11, s = row & 2047;
          if (part == 0)
            qo[(((size_t)bb * HH + h) * SS + s) * HDD + d] = f2bf(v * 0.18033688f); // 0.125*log2(e)
          else if (part == 1)
            ko[(((size_t)bb * HH + h) * SS + s) * HDD + d] = f2bf(v);
          else {
            const int q2 = (s >> 2) & 15;
            const int tau = (q2 & 8) | ((q2 & 3) << 1) | ((q2 >> 2) & 1);
            vo[(((size_t)bb * HH + h) * HDD + d) * SS + (s & ~63) + (tau << 2) + (s & 3)] = f2bf(v);
          }
        } else {
          co[(size_t)row * N + col] = v;
        }
      }
    }
  }
}

// Flash attention (round-11 version, unchanged): QBLK=128, swapped-operand
// QK^T, P in registers, tau-interleaved V -> single-b128 PV reads, K/V dbuf
// LDS, exp2 softmax, defer-max, T1 XCD swizzle.
__global__ __launch_bounds__(256)
void attn_fwd(const short* __restrict__ Q, const short* __restrict__ K,
              const short* __restrict__ V, short* __restrict__ Y) {
  __shared__ short sK[2][64 * 64];
  __shared__ short sV[2][64 * 64];
  const int2 sw = xcd_swizzle();
  const int bh = sw.y;
  const int bx = sw.x;
  const int tid = threadIdx.x, lane = tid & 63, w = tid >> 6;
  const size_t bqk = (size_t)bh * (SS * HDD);
  const size_t bv  = (size_t)bh * (HDD * SS);
  const int b = bh >> 4, h = bh & 15;
  const int lr = lane & 15;
  const int lg = lane >> 4;
  const int lm = lr & 7;

  const int e0 = w * 64 + lane;
  const int e1 = 256 + e0;
  const int r0 = e0 >> 3, s0 = ((e0 & 7) ^ (r0 & 7)) * 8;
  const int r1 = e1 >> 3, s1 = ((e1 & 7) ^ (r1 & 7)) * 8;

  for (int qsel = 0; qsel < 2; ++qsel) {
    const int qt = qsel ? (NQT - 1 - bx) : bx;
    const int q0 = qt * 128;
    const int nkv = 2 * qt + 2;

    __syncthreads();

    {
      const short* gK = K + bqk;
      const short* gV = V + bv;
      gload_lds16(gK + (size_t)r0 * HDD + s0, &sK[0][e0 * 8]);
      gload_lds16(gV + (size_t)r0 * SS + s0, &sV[0][e0 * 8]);
      gload_lds16(gK + (size_t)r1 * HDD + s1, &sK[0][e1 * 8]);
      gload_lds16(gV + (size_t)r1 * SS + s1, &sV[0][e1 * 8]);
    }

    const int qbase = q0 + w * 32;
    bf16x8 qf[2][2];
#pragma unroll
    for (int g = 0; g < 2; ++g)
#pragma unroll
      for (int ks = 0; ks < 2; ++ks)
        qf[g][ks] = *(const bf16x8*)&Q[bqk + (size_t)(qbase + g * 16 + lr) * HDD + ks * 32 + lg * 8];

    f32x4 accO[2][4] = {};
    float m_[2] = {-1e30f, -1e30f}, l_[2] = {0.f, 0.f};

    int cur = 0;
    for (int kt = 0; kt < nkv; ++kt) {
      const int kc0 = kt * 64;
      __syncthreads();
      if (kt < nkv - 1) {
        const short* gK = K + bqk + (size_t)(kc0 + 64) * 64;
        const short* gV = V + bv + kc0 + 64;
        gload_lds16(gK + (size_t)r0 * HDD + s0, &sK[cur ^ 1][e0 * 8]);
        gload_lds16(gV + (size_t)r0 * SS + s0, &sV[cur ^ 1][e0 * 8]);
        gload_lds16(gK + (size_t)r1 * HDD + s1, &sK[cur ^ 1][e1 * 8]);
        gload_lds16(gV + (size_t)r1 * SS + s1, &sV[cur ^ 1][e1 * 8]);
      }

      f32x4 st[2][4] = {};
#pragma unroll
      for (int ks = 0; ks < 2; ++ks) {
#pragma unroll
        for (int nf = 0; nf < 4; ++nf) {
          const int row = nf * 16 + lr;
          const bf16x8 kf = *(const bf16x8*)&sK[cur][row * 64 + (((ks << 2) + lg) ^ lm) * 8];
          st[0][nf] = __builtin_amdgcn_mfma_f32_16x16x32_bf16(kf, qf[0][ks], st[0][nf], 0, 0, 0);
          st[1][nf] = __builtin_amdgcn_mfma_f32_16x16x32_bf16(kf, qf[1][ks], st[1][nf], 0, 0, 0);
        }
      }
      if (kt >= nkv - 2) {
#pragma unroll
        for (int g = 0; g < 2; ++g) {
          const int q = qbase + g * 16 + lr;
#pragma unroll
          for (int nf = 0; nf < 4; ++nf)
#pragma unroll
            for (int r = 0; r < 4; ++r) {
              const int k = kc0 + nf * 16 + lg * 4 + r;
              if (k > q) st[g][nf][r] = -1e30f;
            }
        }
      }

      unsigned u[2][4][2];
#pragma unroll
      for (int g = 0; g < 2; ++g) {
        float rm = -1e30f;
#pragma unroll
        for (int r = 0; r < 4; ++r)
          rm = fmaxf(rm, fmaxf(fmaxf(st[g][0][r], st[g][1][r]), fmaxf(st[g][2][r], st[g][3][r])));
        rm = fmaxf(rm, __shfl_xor(rm, 16));
        rm = fmaxf(rm, __shfl_xor(rm, 32));

        const bool need = rm > m_[g] + 11.5416f;
        if (__any(need)) {
          const float mn = fmaxf(m_[g], rm);
          const float scale = fexp2(m_[g] - mn);
          m_[g] = mn;
          l_[g] *= scale;
#pragma unroll
          for (int r = 0; r < 4; ++r) {
            const float scl = __shfl(scale, (lane & 48) + (lg << 2) + r);
#pragma unroll
            for (int df = 0; df < 4; ++df) accO[g][df][r] *= scl;
          }
        }

        float rs = 0.f;
#pragma unroll
        for (int nf = 0; nf < 4; ++nf)
#pragma unroll
          for (int r = 0; r < 4; ++r) {
            const float p = fexp2(st[g][nf][r] - m_[g]);
            st[g][nf][r] = p;
            rs += p;
          }
        rs += __shfl_xor(rs, 16);
        rs += __shfl_xor(rs, 32);
        l_[g] += rs;

#pragma unroll
        for (int nf = 0; nf < 4; ++nf) {
          u[g][nf][0] = cvtpk(st[g][nf][0], st[g][nf][1]);
          u[g][nf][1] = cvtpk(st[g][nf][2], st[g][nf][3]);
        }
      }

#pragma unroll
      for (int c = 0; c < 2; ++c) {
        int4 pw0, pw1;
        pw0.x = (int)u[0][2 * c][0]; pw0.y = (int)u[0][2 * c][1];
        pw0.z = (int)u[0][2 * c + 1][0]; pw0.w = (int)u[0][2 * c + 1][1];
        pw1.x = (int)u[1][2 * c][0]; pw1.y = (int)u[1][2 * c][1];
        pw1.z = (int)u[1][2 * c + 1][0]; pw1.w = (int)u[1][2 * c + 1][1];
        const bf16x8 pf0 = __builtin_bit_cast(bf16x8, pw0);
        const bf16x8 pf1 = __builtin_bit_cast(bf16x8, pw1);
        const int slot = (((c << 2) + lg) ^ lm) * 8;
#pragma unroll
        for (int df = 0; df < 4; ++df) {
          const bf16x8 vf = *(const bf16x8*)&sV[cur][(df * 16 + lr) * 64 + slot];
          accO[0][df] = __builtin_amdgcn_mfma_f32_16x16x32_bf16(pf0, vf, accO[0][df], 0, 0, 0);
          accO[1][df] = __builtin_amdgcn_mfma_f32_16x16x32_bf16(pf1, vf, accO[1][df], 0, 0, 0);
        }
      }
      cur ^= 1;
    }

#pragma unroll
    for (int g = 0; g < 2; ++g)
#pragma unroll
      for (int r = 0; r < 4; ++r) {
        const float lv = __shfl(l_[g], (lane & 48) + (lg << 2) + r);
        const float inv = frcp(lv);
        const int srow2 = qbase + g * 16 + lg * 4 + r;
#pragma unroll
        for (int df = 0; df < 4; ++df) {
          const int dcol = h * HDD + df * 16 + lr;
          Y[((size_t)b * SS + srow2) * DD + dcol] = f2bf(accO[g][df][r] * inv);
        }
      }
  }
}

extern "C" void kernel_launch(void* const* d_in, const int* in_sizes, int n_in,
                              void* d_out, int out_size, void* d_ws, size_t ws_size,
                              hipStream_t stream) {
  const float* x     = (const float*)d_in[0];
  const float* w_qkv = (const float*)d_in[1];
  const float* b_qkv = (const float*)d_in[2];
  const float* w_out = (const float*)d_in[3];
  const float* b_out = (const float*)d_in[4];
  float* out = (float*)d_out;

  const size_t nx = (size_t)MM * DD;        // 8388608
  const size_t nwq = (size_t)3 * DD * DD;   // 3145728
  const size_t nwo = (size_t)DD * DD;       // 1048576

  short* x_bf    = (short*)d_ws;
  short* wqkv_bf = x_bf + nx;
  short* wout_bf = wqkv_bf + nwq;
  short* q_ws    = wout_bf + nwo;
  short* k_ws    = q_ws + nx;
  short* v_ws    = k_ws + nx;
  short* y_ws    = v_ws + nx;

  cast3_f32_bf16<<<dim3(2048), dim3(256), 0, stream>>>(
      x, (unsigned long long*)x_bf, (int)(nx / 4),
      w_qkv, (unsigned long long*)wqkv_bf, (int)(nwq / 4),
      w_out, (unsigned long long*)wout_bf, (int)(nwo / 4));

  // GEMM1: QKV, 128x128 tiles, grid 24x64 = 1536
  gemm_bt<0><<<dim3(3 * DD / 128, MM / 128), dim3(256), 0, stream>>>(
      x_bf, wqkv_bf, b_qkv, q_ws, k_ws, v_ws, nullptr, MM, 3 * DD, DD);

  attn_fwd<<<dim3(NQT / 2, BB * HH), dim3(256), 0, stream>>>(q_ws, k_ws, v_ws, y_ws);

  // GEMM2: out-proj, 128x128 tiles, grid 8x64 = 512
  gemm_bt<1><<<dim3(DD / 128, MM / 128), dim3(256), 0, stream>>>(
      y_ws, wout_bf, b_out, nullptr, nullptr, nullptr, out, MM, DD, DD);
}